// Round 3
// baseline (1235.678 us; speedup 1.0000x reference)
//
#include <hip/hip_runtime.h>

typedef unsigned short u16;
typedef unsigned long long u64;
typedef __attribute__((ext_vector_type(8))) __bf16 bf16x8;
typedef __attribute__((ext_vector_type(4))) float floatx4;

// Problem constants
#define TT 64
#define BB 32
#define HS 512
#define VS 32000
#define NBLKV (VS / 64)   // 500 column-blocks in the final GEMM

__device__ inline u16 f2bf(float f) {
  unsigned u = __float_as_uint(f);
  unsigned r = (u + 0x7FFFu + ((u >> 16) & 1u)) >> 16;
  return (u16)r;
}

__device__ inline bf16x8 ld8(const u16* p) {
  return *reinterpret_cast<const bf16x8*>(p);
}

// ---------------------------------------------------------------------------
// Prep: cast W_hh -> bf16, gather x = emb[dst] -> bf16, h0 -> hseq[0], zero
// the padded arrival counters (32 x 64 words = 8 KB). 4096 x 256 threads.
// ---------------------------------------------------------------------------
__global__ void prep_k(const float* __restrict__ Whh_f, const float* __restrict__ emb,
                       const int* __restrict__ dst, const float* __restrict__ h0,
                       u16* __restrict__ Whh_bf, u16* __restrict__ Xbf,
                       u16* __restrict__ hseq, unsigned* __restrict__ flags)
{
  const int i = blockIdx.x * 256 + threadIdx.x;      // 0 .. 2048*512-1
  Whh_bf[i] = f2bf(Whh_f[i]);
  const int row = i >> 9, k = i & 511;               // row = t*32+b
  const int tok = dst[row];
  Xbf[i] = f2bf(emb[(size_t)tok * HS + k]);
  if (i < BB * HS) hseq[i] = f2bf(h0[i]);
  if (i < 2048) flags[i] = 0u;                       // padded counters (256B/blk)
}

// ---------------------------------------------------------------------------
// GEMM: C[M x Ncols] = A(bf16, [M][512]) @ Bsrc(f32, [N][512])^T  (+ bias)
// One wg = 64-column block of B staged to LDS as bf16 (XOR-swizzled, 64 KB).
// FINAL=false: write f32 pregates row-major (+b_ih+b_hh).
// FINAL=true: write f32 logits transposed into d_out (+b_out) and store
// per-(block,row) partial sum(exp) into part[blockIdx.x][row] — no atomics.
// ---------------------------------------------------------------------------
template<bool FINAL>
__launch_bounds__(256, 2)
__global__ void gemm_k(const u16* __restrict__ A, const float* __restrict__ Bsrc,
                       const float* __restrict__ bias0, const float* __restrict__ bias1,
                       float* __restrict__ Cout, float* __restrict__ part,
                       int Mtiles)
{
  extern __shared__ u16 lds[];                       // 64 rows x 512 u16, swizzled
  const int n0 = blockIdx.x * 64;

  // Stage B block: 64 rows x 512 f32 -> bf16 LDS with 16B-chunk XOR swizzle.
  for (int idx = threadIdx.x; idx < 64 * 128; idx += 256) {
    const int r = idx >> 7, c4 = idx & 127;
    const float4 f = *reinterpret_cast<const float4*>(Bsrc + (size_t)(n0 + r) * HS + c4 * 4);
    const unsigned lo = (unsigned)f2bf(f.x) | ((unsigned)f2bf(f.y) << 16);
    const unsigned hi = (unsigned)f2bf(f.z) | ((unsigned)f2bf(f.w) << 16);
    const int chunk = c4 >> 1, half = c4 & 1;
    const int sw = chunk ^ (r & 7);
    *reinterpret_cast<uint2*>(&lds[r * 512 + sw * 8 + half * 4]) = make_uint2(lo, hi);
  }
  __syncthreads();

  const int wave = threadIdx.x >> 6, lane = threadIdx.x & 63;
  const int q = lane >> 4, col = lane & 15;
  const int mt_per = Mtiles >> 2;                    // m-tiles per wave
  const int mtile0 = blockIdx.y * Mtiles + wave * mt_per;

  for (int mp = 0; mp < (mt_per >> 1); ++mp) {
    const int mt = mtile0 + mp * 2;
    const u16* Ap0 = A + (size_t)(mt * 16 + col) * HS + q * 8;
    const u16* Ap1 = Ap0 + 16 * HS;

    floatx4 acc[2][4];
    const floatx4 zero = {0.f, 0.f, 0.f, 0.f};
#pragma unroll
    for (int m = 0; m < 2; ++m)
#pragma unroll
      for (int n = 0; n < 4; ++n) acc[m][n] = zero;

#pragma unroll
    for (int kb = 0; kb < 16; ++kb) {
      const bf16x8 a0 = ld8(Ap0 + kb * 32);
      const bf16x8 a1 = ld8(Ap1 + kb * 32);
#pragma unroll
      for (int n = 0; n < 4; ++n) {
        const int br = n * 16 + col;
        const bf16x8 b = ld8(&lds[br * 512 + (((kb * 4 + q) ^ (br & 7))) * 8]);
        acc[0][n] = __builtin_amdgcn_mfma_f32_16x16x32_bf16(a0, b, acc[0][n], 0, 0, 0);
        acc[1][n] = __builtin_amdgcn_mfma_f32_16x16x32_bf16(a1, b, acc[1][n], 0, 0, 0);
      }
    }

#pragma unroll
    for (int m = 0; m < 2; ++m) {
#pragma unroll
      for (int r2 = 0; r2 < 4; ++r2) {
        const int row = (mt + m) * 16 + q * 4 + r2;  // row = t*32+b
        if (FINAL) {
          const int t = row >> 5, b = row & 31;
          float* orow = Cout + (size_t)(b * TT + t) * VS;
          float es = 0.f;
#pragma unroll
          for (int n = 0; n < 4; ++n) {
            const int gc = n0 + n * 16 + col;
            const float v = acc[m][n][r2] + bias0[gc];
            orow[gc] = v;
            es += __expf(v);
          }
          es += __shfl_xor(es, 1);
          es += __shfl_xor(es, 2);
          es += __shfl_xor(es, 4);
          es += __shfl_xor(es, 8);
          if (col == 0) part[(size_t)blockIdx.x * (TT * BB) + row] = es;
        } else {
          float* crow = Cout + (size_t)row * 2048;
#pragma unroll
          for (int n = 0; n < 4; ++n) {
            const int gc = n0 + n * 16 + col;
            crow[gc] = acc[m][n][r2] + bias0[gc] + bias1[gc];
          }
        }
      }
    }
  }
}

// ---------------------------------------------------------------------------
// Persistent LSTM: 32 blocks x 512 (8 waves/block). Block b owns units
// [16b, 16b+16), all 4 gates; its 64 Whh rows staged to LDS once (64 KB,
// XOR-swizzled). One 16x16 output tile per wave = all 4 gates of 4 units;
// gate combine via 3 in-wave shuffles; c stays in registers. h stores are
// RELAXED agent-scope packed 8B write-through.
//
// Handshake (NEW — barrier-free step loop):
//  * per-block arrival counter cnt[blk*64], one 256B line each (no false
//    sharing; parallel LLC slices). Each wave: s_waitcnt vmcnt(0) on its OWN
//    h stores, then one relaxed agent atomicAdd(+1), fire-and-forget.
//    cnt == 8*(t+1)  <=>  all 8 waves of that block have ACKED h stores.
//  * wave 0 polls the 32 counters (lane i -> cnt[i*64], distinct lines) and
//    publishes a monotonic LDS token; waves 1-7 spin on the LDS token
//    (local, ~30cy) — NO __syncthreads in the loop, so wave stragglers
//    overlap instead of serializing through 2 block barriers per step.
//  * Counters are step-synchronized: no wave can issue its step-(t+1) add
//    before the global step-t condition, so ">= 8*(t+1)" is exact.
//  * Visibility without cache maintenance: adds follow acked write-through
//    stores; readers first-touch each hseq slice only post-token, so plain
//    loads are fresh by construction (no buffer_inv, L2 stays warm).
// ---------------------------------------------------------------------------
__launch_bounds__(512, 1)
__global__ void lstm_k(const float* __restrict__ pregates, const u16* __restrict__ Whh,
                       const float* __restrict__ c0, u16* __restrict__ hseq,
                       unsigned* __restrict__ cnt)
{
  extern __shared__ u16 lds[];                       // 64x512 u16 weights + token
  unsigned* tokp = reinterpret_cast<unsigned*>(&lds[32768]);  // byte 65536
  const int tid = threadIdx.x;
  const int blk = blockIdx.x;

  // Stage this block's 64 Whh rows (bf16) into LDS, XOR-swizzled.
  for (int idx = tid; idx < 64 * 64; idx += 512) {
    const int R = idx >> 6, c = idx & 63;            // row, 16B-chunk
    const int grow = (R & 3) * 512 + blk * 16 + (R >> 2);
    const uint4 v = *reinterpret_cast<const uint4*>(Whh + (size_t)grow * HS + c * 8);
    *reinterpret_cast<uint4*>(&lds[R * 512 + ((c ^ (R & 7)) * 8)]) = v;
  }
  if (tid == 0) *tokp = 0u;

  const int wave = tid >> 6, lane = tid & 63;
  const int q = lane >> 4, col = lane & 15;
  const int nt = wave >> 1, mt = wave & 1;
  const int R = nt * 16 + col;                       // block-local gate-row
  const int gate = col & 3;
  const int unit = blk * 16 + nt * 4 + (col >> 2);
  const int batch0 = mt * 16 + q * 4;

  float c_[4];
#pragma unroll
  for (int r = 0; r < 4; ++r)
    c_[r] = c0[(size_t)(batch0 + r) * HS + unit];

  float pg[4];
#pragma unroll
  for (int r = 0; r < 4; ++r)
    pg[r] = pregates[(size_t)(batch0 + r) * 2048 + gate * 512 + unit];

  __syncthreads();                                   // LDS staged + token init

  for (int t = 0; t < TT; ++t) {
    const u16* Ap = hseq + (size_t)t * (BB * HS) + (size_t)(mt * 16 + col) * HS + q * 8;
    floatx4 acc = {0.f, 0.f, 0.f, 0.f};
#pragma unroll
    for (int kb = 0; kb < 16; ++kb)
      acc = __builtin_amdgcn_mfma_f32_16x16x32_bf16(
          ld8(Ap + kb * 32),
          ld8(&lds[R * 512 + (((kb * 4 + q) ^ (R & 7)) * 8)]),
          acc, 0, 0, 0);

    u16* hnext = hseq + (size_t)(t + 1) * (BB * HS);
#pragma unroll
    for (int r = 0; r < 4; ++r) {
      const float vv = acc[r] + pg[r];
      const float x1 = __shfl_xor(vv, 1);            // gate g^1
      const float x2 = __shfl_xor(vv, 2);            // gate g^2
      const float x3 = __shfl_xor(x1, 2);            // gate g^3
      // valid mapping for gate==0 lanes: i=vv f=x1 g=x2 o=x3
      const float si = 1.f / (1.f + __expf(-vv));
      const float sf = 1.f / (1.f + __expf(-x1));
      const float eg = __expf(2.f * x2);
      const float tg = 1.f - 2.f / (eg + 1.f);       // tanh, inf-safe
      const float so = 1.f / (1.f + __expf(-x3));
      c_[r] = sf * c_[r] + si * tg;
      const float ec = __expf(2.f * c_[r]);
      const float tc = 1.f - 2.f / (ec + 1.f);
      // Pack units (col 0,4,8,12 hold units +0..+3) into one u64 on col==0.
      const unsigned w = (unsigned)f2bf(so * tc);    // garbage on gate!=0 lanes (finite, unused)
      const unsigned w4 = __shfl_xor(w, 4);          // col0: unit+1 ; col8: unit+3
      const unsigned lo = w | (w4 << 16);
      const unsigned hi = __shfl_xor(lo, 8);         // col0: units +2,+3
      if (col == 0) {
        const u64 v = (u64)lo | ((u64)hi << 32);
        __hip_atomic_store(
            reinterpret_cast<u64*>(&hnext[(size_t)(batch0 + r) * HS + blk * 16 + nt * 4]),
            v, __ATOMIC_RELAXED, __HIP_MEMORY_SCOPE_AGENT);
      }
    }

    if (t + 1 < TT) {
      // Own h stores acked at the coherence point, then signal arrival.
      asm volatile("s_waitcnt vmcnt(0)" ::: "memory");
      if (lane == 0)
        __hip_atomic_fetch_add(&cnt[blk * 64], 1u,
                               __ATOMIC_RELAXED, __HIP_MEMORY_SCOPE_AGENT);
      // prefetch next step's pregates (overlaps the wait)
#pragma unroll
      for (int r = 0; r < 4; ++r)
        pg[r] = pregates[(size_t)((t + 1) * BB + batch0 + r) * 2048 + gate * 512 + unit];

      const unsigned tgt = 8u * (unsigned)(t + 1);
      if (wave == 0) {
        while (true) {
          unsigned f = tgt;
          if (lane < 32)
            f = __hip_atomic_load(&cnt[lane * 64], __ATOMIC_RELAXED, __HIP_MEMORY_SCOPE_AGENT);
          if (__all(f >= tgt)) break;
          __builtin_amdgcn_s_sleep(1);
        }
        __hip_atomic_store(tokp, (unsigned)(t + 1),
                           __ATOMIC_RELAXED, __HIP_MEMORY_SCOPE_WORKGROUP);
      } else {
        while (__hip_atomic_load(tokp, __ATOMIC_RELAXED, __HIP_MEMORY_SCOPE_WORKGROUP)
               < (unsigned)(t + 1))
          __builtin_amdgcn_s_sleep(1);
      }
      asm volatile("" ::: "memory");                 // compiler-only acquire
    }
  }
}

// ---------------------------------------------------------------------------
// logZ[row] = log( sum_p part[p][row] ), one wave per row (2048 blocks x 64).
// ---------------------------------------------------------------------------
__global__ void logz_k(const float* __restrict__ part, float* __restrict__ logZ)
{
  const int row = blockIdx.x;
  const int lane = threadIdx.x;
  float s = 0.f;
  for (int p = lane; p < NBLKV; p += 64)
    s += part[(size_t)p * (TT * BB) + row];
  s += __shfl_xor(s, 32);
  s += __shfl_xor(s, 16);
  s += __shfl_xor(s, 8);
  s += __shfl_xor(s, 4);
  s += __shfl_xor(s, 2);
  s += __shfl_xor(s, 1);
  if (lane == 0) logZ[row] = __logf(s);
}

// ---------------------------------------------------------------------------
// out[b][t][v] -= logZ[t*32+b], vectorized float4, in place.
// ---------------------------------------------------------------------------
__global__ void norm_k(float* __restrict__ out, const float* __restrict__ logZ)
{
  const int i = blockIdx.x * 256 + threadIdx.x;
  const int rowi = i / (VS / 4);                    // = b*64 + t
  const int b = rowi >> 6, t = rowi & 63;
  const float lz = logZ[t * BB + b];
  float4* p = reinterpret_cast<float4*>(out) + i;
  float4 v = *p;
  v.x -= lz; v.y -= lz; v.z -= lz; v.w -= lz;
  *p = v;
}

// ---------------------------------------------------------------------------
extern "C" void kernel_launch(void* const* d_in, const int* in_sizes, int n_in,
                              void* d_out, int out_size, void* d_ws, size_t ws_size,
                              hipStream_t stream) {
  const float* h0    = (const float*)d_in[1];
  const float* c0    = (const float*)d_in[2];
  const float* emb   = (const float*)d_in[3];
  const float* W_ih  = (const float*)d_in[4];
  const float* W_hh  = (const float*)d_in[5];
  const float* b_ih  = (const float*)d_in[6];
  const float* b_hh  = (const float*)d_in[7];
  const float* W_out = (const float*)d_in[8];
  const float* b_out = (const float*)d_in[9];
  const int*   dst   = (const int*)d_in[10];
  float* out = (float*)d_out;

  char* ws = (char*)d_ws;
  size_t off = 0;
  auto alloc = [&](size_t bytes) {
    void* p = ws + off;
    off = (off + bytes + 255) & ~(size_t)255;
    return p;
  };
  u16*      Whh_bf   = (u16*)alloc((size_t)2048 * HS * 2);           // 2 MB
  u16*      Xbf      = (u16*)alloc((size_t)TT * BB * HS * 2);        // 2 MB
  u16*      hseq     = (u16*)alloc((size_t)(TT + 1) * BB * HS * 2);  // 2.1 MB
  float*    pregates = (float*)alloc((size_t)TT * BB * 2048 * 4);    // 16.8 MB
  float*    logZ     = (float*)alloc((size_t)TT * BB * 4);
  unsigned* flags    = (unsigned*)alloc(2048 * 4);                   // 8 KB padded
  (void)ws_size; (void)in_sizes; (void)n_in; (void)out_size;

  // part[500][2048] partial exp-sums alias the pregates buffer (dead after
  // lstm_k; 4.1 MB << 16.8 MB).
  float* part = pregates;

  // 1) casts + embedding gather + init
  prep_k<<<4096, 256, 0, stream>>>(W_hh, emb, dst, h0, Whh_bf, Xbf, hseq, flags);

  // 2) pregates = Xbf @ W_ih^T + b_ih + b_hh   (M=2048 split in 2, N=2048)
  gemm_k<false><<<dim3(32, 2), 256, 65536, stream>>>(Xbf, W_ih, b_ih, b_hh,
                                                     pregates, nullptr, 64);

  // 3) 64-step LSTM recurrence (persistent, barrier-free handshake)
  lstm_k<<<32, 512, 65536 + 256, stream>>>(pregates, Whh_bf, c0, hseq, flags);

  // 4) logits = H @ W_out^T + b_out -> d_out (transposed) + partial rowsums
  gemm_k<true><<<dim3(NBLKV, 1), 256, 65536, stream>>>(hseq + BB * HS, W_out, b_out,
                                                       nullptr, out, part, 128);

  // 5) logZ[row] = log(sum_p part[p][row])
  logz_k<<<TT * BB, 64, 0, stream>>>(part, logZ);

  // 6) out -= logZ[row]  (in place)
  norm_k<<<64000, 256, 0, stream>>>(out, logZ);
}

// Round 4
// 1012.292 us; speedup vs baseline: 1.2207x; 1.2207x over previous
//
#include <hip/hip_runtime.h>

typedef unsigned short u16;
typedef unsigned long long u64;
typedef __attribute__((ext_vector_type(8))) __bf16 bf16x8;
typedef __attribute__((ext_vector_type(4))) float floatx4;

// Problem constants
#define TT 64
#define BB 32
#define HS 512
#define VS 32000
#define NBLKV (VS / 64)   // 500 column-blocks in the final GEMM

__device__ inline u16 f2bf(float f) {
  unsigned u = __float_as_uint(f);
  unsigned r = (u + 0x7FFFu + ((u >> 16) & 1u)) >> 16;
  return (u16)r;
}

__device__ inline bf16x8 ld8(const u16* p) {
  return *reinterpret_cast<const bf16x8*>(p);
}

// ---------------------------------------------------------------------------
// Prep: cast W_hh -> bf16, gather x = emb[dst] -> bf16, h0 -> hseq[0], zero
// barrier flags. 4096 blocks x 256 = 1,048,576 threads (exact).
// ---------------------------------------------------------------------------
__global__ void prep_k(const float* __restrict__ Whh_f, const float* __restrict__ emb,
                       const int* __restrict__ dst, const float* __restrict__ h0,
                       u16* __restrict__ Whh_bf, u16* __restrict__ Xbf,
                       u16* __restrict__ hseq, unsigned* __restrict__ flags)
{
  const int i = blockIdx.x * 256 + threadIdx.x;      // 0 .. 2048*512-1
  Whh_bf[i] = f2bf(Whh_f[i]);
  const int row = i >> 9, k = i & 511;               // row = t*32+b
  const int tok = dst[row];
  Xbf[i] = f2bf(emb[(size_t)tok * HS + k]);
  if (i < BB * HS) hseq[i] = f2bf(h0[i]);
  if (i < 64) flags[i] = 0u;
}

// ---------------------------------------------------------------------------
// GEMM: C[M x Ncols] = A(bf16, [M][512]) @ Bsrc(f32, [N][512])^T  (+ bias)
// One wg = 64-column block of B staged to LDS as bf16 (XOR-swizzled, 64 KB).
// RESTRUCTURED (this round): 512 threads (8 waves, 2/SIMD) and 4-m-tile
// grouping — each LDS B fragment feeds 4 MFMAs instead of 2, halving the
// ds_read_b128 port pressure (was ~41 us/CU, the modeled binding port);
// A-address reuse doubles. Math, LDS layout, and swizzle are unchanged.
// FINAL=false: write f32 pregates row-major (+b_ih+b_hh).
// FINAL=true: write f32 logits transposed into d_out (+b_out) and store
// per-(block,row) partial sum(exp) into part[blockIdx.x][row] — no atomics.
// ---------------------------------------------------------------------------
template<bool FINAL>
__launch_bounds__(512, 2)
__global__ void gemm_k(const u16* __restrict__ A, const float* __restrict__ Bsrc,
                       const float* __restrict__ bias0, const float* __restrict__ bias1,
                       float* __restrict__ Cout, float* __restrict__ part,
                       int Mtiles)
{
  extern __shared__ u16 lds[];                       // 64 rows x 512 u16, swizzled
  const int n0 = blockIdx.x * 64;

  // Stage B block: 64 rows x 512 f32 -> bf16 LDS with 16B-chunk XOR swizzle.
  for (int idx = threadIdx.x; idx < 64 * 128; idx += 512) {
    const int r = idx >> 7, c4 = idx & 127;
    const float4 f = *reinterpret_cast<const float4*>(Bsrc + (size_t)(n0 + r) * HS + c4 * 4);
    const unsigned lo = (unsigned)f2bf(f.x) | ((unsigned)f2bf(f.y) << 16);
    const unsigned hi = (unsigned)f2bf(f.z) | ((unsigned)f2bf(f.w) << 16);
    const int chunk = c4 >> 1, half = c4 & 1;
    const int sw = chunk ^ (r & 7);
    *reinterpret_cast<uint2*>(&lds[r * 512 + sw * 8 + half * 4]) = make_uint2(lo, hi);
  }
  __syncthreads();

  const int wave = threadIdx.x >> 6, lane = threadIdx.x & 63;
  const int q = lane >> 4, col = lane & 15;
  const int mt_per = Mtiles >> 3;                    // m-tiles per wave (8 waves)
  const int mtile0 = blockIdx.y * Mtiles + wave * mt_per;

  for (int mp = 0; mp < (mt_per >> 2); ++mp) {
    const int mt = mtile0 + mp * 4;
    const u16* Ap = A + (size_t)(mt * 16 + col) * HS + q * 8;

    floatx4 acc[4][4];
    const floatx4 zero = {0.f, 0.f, 0.f, 0.f};
#pragma unroll
    for (int m = 0; m < 4; ++m)
#pragma unroll
      for (int n = 0; n < 4; ++n) acc[m][n] = zero;

#pragma unroll
    for (int kb = 0; kb < 16; ++kb) {
      bf16x8 a[4];
#pragma unroll
      for (int m = 0; m < 4; ++m)
        a[m] = ld8(Ap + (size_t)m * 16 * HS + kb * 32);
#pragma unroll
      for (int n = 0; n < 4; ++n) {
        const int br = n * 16 + col;
        const bf16x8 b = ld8(&lds[br * 512 + (((kb * 4 + q) ^ (br & 7))) * 8]);
#pragma unroll
        for (int m = 0; m < 4; ++m)
          acc[m][n] = __builtin_amdgcn_mfma_f32_16x16x32_bf16(a[m], b, acc[m][n], 0, 0, 0);
      }
    }

#pragma unroll
    for (int m = 0; m < 4; ++m) {
#pragma unroll
      for (int r2 = 0; r2 < 4; ++r2) {
        const int row = (mt + m) * 16 + q * 4 + r2;  // row = t*32+b
        if (FINAL) {
          const int t = row >> 5, b = row & 31;
          float* orow = Cout + (size_t)(b * TT + t) * VS;
          float es = 0.f;
#pragma unroll
          for (int n = 0; n < 4; ++n) {
            const int gc = n0 + n * 16 + col;
            const float v = acc[m][n][r2] + bias0[gc];
            orow[gc] = v;
            es += __expf(v);
          }
          es += __shfl_xor(es, 1);
          es += __shfl_xor(es, 2);
          es += __shfl_xor(es, 4);
          es += __shfl_xor(es, 8);
          if (col == 0) part[(size_t)blockIdx.x * (TT * BB) + row] = es;
        } else {
          float* crow = Cout + (size_t)row * 2048;
#pragma unroll
          for (int n = 0; n < 4; ++n) {
            const int gc = n0 + n * 16 + col;
            crow[gc] = acc[m][n][r2] + bias0[gc] + bias1[gc];
          }
        }
      }
    }
  }
}

// ---------------------------------------------------------------------------
// Persistent LSTM: 32 blocks x 512 (8 waves/block). Block b owns units
// [16b, 16b+16), all 4 gates; its 64 Whh rows staged to LDS once (64 KB,
// XOR-swizzled). One 16x16 output tile per wave = all 4 gates of 4 units;
// gate combine via 3 in-wave shuffles; c stays in registers.
//
// Handshake: EXACT Round-2 scheme (verified 404 us; the R3 padded-counter
// variant regressed to 496 us — 32-line poll gather + contended atomics
// cost more than the two block barriers they replaced). h stores RELAXED
// agent-scope packed 8B write-through; __syncthreads drains vmcnt(0);
// relaxed flag store by tid 0; wave-0 lanes poll the 32 DENSE flags (2
// cache lines, coalesced); compiler-only acquire (no buffer_inv) since
// readers first-touch each hseq slice only post-flag and write-through
// stores never leave stale L2 lines.
// ---------------------------------------------------------------------------
__launch_bounds__(512, 1)
__global__ void lstm_k(const float* __restrict__ pregates, const u16* __restrict__ Whh,
                       const float* __restrict__ c0, u16* __restrict__ hseq,
                       unsigned* __restrict__ flags)
{
  extern __shared__ u16 lds[];                       // 64 rows x 512 u16
  const int tid = threadIdx.x;
  const int blk = blockIdx.x;

  // Stage this block's 64 Whh rows (bf16) into LDS, XOR-swizzled.
  for (int idx = tid; idx < 64 * 64; idx += 512) {
    const int R = idx >> 6, c = idx & 63;            // row, 16B-chunk
    const int grow = (R & 3) * 512 + blk * 16 + (R >> 2);
    const uint4 v = *reinterpret_cast<const uint4*>(Whh + (size_t)grow * HS + c * 8);
    *reinterpret_cast<uint4*>(&lds[R * 512 + ((c ^ (R & 7)) * 8)]) = v;
  }

  const int wave = tid >> 6, lane = tid & 63;
  const int q = lane >> 4, col = lane & 15;
  const int nt = wave >> 1, mt = wave & 1;
  const int R = nt * 16 + col;                       // block-local gate-row
  const int gate = col & 3;
  const int unit = blk * 16 + nt * 4 + (col >> 2);
  const int batch0 = mt * 16 + q * 4;

  float c_[4];
#pragma unroll
  for (int r = 0; r < 4; ++r)
    c_[r] = c0[(size_t)(batch0 + r) * HS + unit];

  float pg[4];
#pragma unroll
  for (int r = 0; r < 4; ++r)
    pg[r] = pregates[(size_t)(batch0 + r) * 2048 + gate * 512 + unit];

  __syncthreads();                                   // LDS staged

  for (int t = 0; t < TT; ++t) {
    const u16* Ap = hseq + (size_t)t * (BB * HS) + (size_t)(mt * 16 + col) * HS + q * 8;
    floatx4 acc = {0.f, 0.f, 0.f, 0.f};
#pragma unroll
    for (int kb = 0; kb < 16; ++kb)
      acc = __builtin_amdgcn_mfma_f32_16x16x32_bf16(
          ld8(Ap + kb * 32),
          ld8(&lds[R * 512 + (((kb * 4 + q) ^ (R & 7)) * 8)]),
          acc, 0, 0, 0);

    u16* hnext = hseq + (size_t)(t + 1) * (BB * HS);
#pragma unroll
    for (int r = 0; r < 4; ++r) {
      const float vv = acc[r] + pg[r];
      const float x1 = __shfl_xor(vv, 1);            // gate g^1
      const float x2 = __shfl_xor(vv, 2);            // gate g^2
      const float x3 = __shfl_xor(x1, 2);            // gate g^3
      // valid mapping for gate==0 lanes: i=vv f=x1 g=x2 o=x3
      const float si = 1.f / (1.f + __expf(-vv));
      const float sf = 1.f / (1.f + __expf(-x1));
      const float eg = __expf(2.f * x2);
      const float tg = 1.f - 2.f / (eg + 1.f);       // tanh, inf-safe
      const float so = 1.f / (1.f + __expf(-x3));
      c_[r] = sf * c_[r] + si * tg;
      const float ec = __expf(2.f * c_[r]);
      const float tc = 1.f - 2.f / (ec + 1.f);
      // Pack units (col 0,4,8,12 hold units +0..+3) into one u64 on col==0.
      const unsigned w = (unsigned)f2bf(so * tc);    // garbage on gate!=0 lanes (finite, unused)
      const unsigned w4 = __shfl_xor(w, 4);          // col0: unit+1 ; col8: unit+3
      const unsigned lo = w | (w4 << 16);
      const unsigned hi = __shfl_xor(lo, 8);         // col0: units +2,+3
      if (col == 0) {
        const u64 v = (u64)lo | ((u64)hi << 32);
        __hip_atomic_store(
            reinterpret_cast<u64*>(&hnext[(size_t)(batch0 + r) * HS + blk * 16 + nt * 4]),
            v, __ATOMIC_RELAXED, __HIP_MEMORY_SCOPE_AGENT);
      }
    }

    if (t + 1 < TT) {
      __syncthreads();   // barrier drain (vmcnt 0) => all write-through h stores agent-visible
      if (tid == 0)
        __hip_atomic_store(&flags[blk], (unsigned)(t + 1),
                           __ATOMIC_RELAXED, __HIP_MEMORY_SCOPE_AGENT);
      asm volatile("" ::: "memory");                 // keep flag store before the poll
      // prefetch next step's pregates (plain loads; L2 stays warm)
#pragma unroll
      for (int r = 0; r < 4; ++r)
        pg[r] = pregates[(size_t)((t + 1) * BB + batch0 + r) * 2048 + gate * 512 + unit];
      if (tid < 64) {
        const unsigned tgt = (unsigned)(t + 1);
        while (true) {
          unsigned f = tgt;
          if (lane < 32)
            f = __hip_atomic_load(&flags[lane], __ATOMIC_RELAXED, __HIP_MEMORY_SCOPE_AGENT);
          if (__all(f >= tgt)) break;
          __builtin_amdgcn_s_sleep(1);
        }
      }
      asm volatile("" ::: "memory");                 // compiler-only acquire (no buffer_inv)
      __syncthreads();
    }
  }
}

// ---------------------------------------------------------------------------
// logZ[row] = log( sum_p part[p][row] ), one wave per row (2048 blocks x 64).
// ---------------------------------------------------------------------------
__global__ void logz_k(const float* __restrict__ part, float* __restrict__ logZ)
{
  const int row = blockIdx.x;
  const int lane = threadIdx.x;
  float s = 0.f;
  for (int p = lane; p < NBLKV; p += 64)
    s += part[(size_t)p * (TT * BB) + row];
  s += __shfl_xor(s, 32);
  s += __shfl_xor(s, 16);
  s += __shfl_xor(s, 8);
  s += __shfl_xor(s, 4);
  s += __shfl_xor(s, 2);
  s += __shfl_xor(s, 1);
  if (lane == 0) logZ[row] = __logf(s);
}

// ---------------------------------------------------------------------------
// out[b][t][v] -= logZ[t*32+b], vectorized float4, in place.
// ---------------------------------------------------------------------------
__global__ void norm_k(float* __restrict__ out, const float* __restrict__ logZ)
{
  const int i = blockIdx.x * 256 + threadIdx.x;
  const int rowi = i / (VS / 4);                    // = b*64 + t
  const int b = rowi >> 6, t = rowi & 63;
  const float lz = logZ[t * BB + b];
  float4* p = reinterpret_cast<float4*>(out) + i;
  float4 v = *p;
  v.x -= lz; v.y -= lz; v.z -= lz; v.w -= lz;
  *p = v;
}

// ---------------------------------------------------------------------------
extern "C" void kernel_launch(void* const* d_in, const int* in_sizes, int n_in,
                              void* d_out, int out_size, void* d_ws, size_t ws_size,
                              hipStream_t stream) {
  const float* h0    = (const float*)d_in[1];
  const float* c0    = (const float*)d_in[2];
  const float* emb   = (const float*)d_in[3];
  const float* W_ih  = (const float*)d_in[4];
  const float* W_hh  = (const float*)d_in[5];
  const float* b_ih  = (const float*)d_in[6];
  const float* b_hh  = (const float*)d_in[7];
  const float* W_out = (const float*)d_in[8];
  const float* b_out = (const float*)d_in[9];
  const int*   dst   = (const int*)d_in[10];
  float* out = (float*)d_out;

  char* ws = (char*)d_ws;
  size_t off = 0;
  auto alloc = [&](size_t bytes) {
    void* p = ws + off;
    off = (off + bytes + 255) & ~(size_t)255;
    return p;
  };
  u16*      Whh_bf   = (u16*)alloc((size_t)2048 * HS * 2);           // 2 MB
  u16*      Xbf      = (u16*)alloc((size_t)TT * BB * HS * 2);        // 2 MB
  u16*      hseq     = (u16*)alloc((size_t)(TT + 1) * BB * HS * 2);  // 2.1 MB
  float*    pregates = (float*)alloc((size_t)TT * BB * 2048 * 4);    // 16.8 MB
  float*    logZ     = (float*)alloc((size_t)TT * BB * 4);
  unsigned* flags    = (unsigned*)alloc(256);
  (void)ws_size; (void)in_sizes; (void)n_in; (void)out_size;

  // part[500][2048] partial exp-sums alias the pregates buffer (dead after
  // lstm_k; 4.1 MB << 16.8 MB).
  float* part = pregates;

  // 1) casts + embedding gather + init
  prep_k<<<4096, 256, 0, stream>>>(W_hh, emb, dst, h0, Whh_bf, Xbf, hseq, flags);

  // 2) pregates = Xbf @ W_ih^T + b_ih + b_hh   (M=2048 split in 2, N=2048)
  gemm_k<false><<<dim3(32, 2), 512, 65536, stream>>>(Xbf, W_ih, b_ih, b_hh,
                                                     pregates, nullptr, 64);

  // 3) 64-step LSTM recurrence (persistent, grid-barriered)
  lstm_k<<<32, 512, 65536, stream>>>(pregates, Whh_bf, c0, hseq, flags);

  // 4) logits = H @ W_out^T + b_out -> d_out (transposed) + partial rowsums
  gemm_k<true><<<dim3(NBLKV, 1), 512, 65536, stream>>>(hseq + BB * HS, W_out, b_out,
                                                       nullptr, out, part, 128);

  // 5) logZ[row] = log(sum_p part[p][row])
  logz_k<<<TT * BB, 64, 0, stream>>>(part, logZ);

  // 6) out -= logZ[row]  (in place)
  norm_k<<<64000, 256, 0, stream>>>(out, logZ);
}